// Round 1
// baseline (524.623 us; speedup 1.0000x reference)
//
#include <hip/hip_runtime.h>
#include <math.h>

#define T 8
#define N 5000
#define E 160000
#define EN (E + N)
#define IN_DIM 64
#define HID 128
#define H 8
#define D 16
#define NC 2
#define MT 32            // rows per k_pg / k_cls block
#define NBN 4            // nodes per k_node block

__device__ __forceinline__ float leaky(float e) { return (e >= 0.0f) ? e : 0.2f * e; }

// fused h=relu(x@Wp+bp); xh=h@Wg; a_s/a_d coef epilogue
__global__ __launch_bounds__(256) void k_pg(const float* __restrict__ x,
                                            const float* __restrict__ Wp,
                                            const float* __restrict__ bp,
                                            const float* __restrict__ Wg,
                                            const float* __restrict__ asrc,
                                            const float* __restrict__ adst,
                                            float* __restrict__ xh,
                                            float* __restrict__ a_s,
                                            float* __restrict__ a_d) {
    __shared__ float xt[MT][IN_DIM];
    __shared__ float ht[MT][HID + 1];
    int row0 = blockIdx.x * MT;
    int tid = threadIdx.x;

    for (int idx = tid; idx < MT * IN_DIM; idx += 256) {
        int r = idx >> 6, k = idx & 63;
        xt[r][k] = x[(size_t)(row0 + r) * IN_DIM + k];
    }
    __syncthreads();

    int cg = tid & 31;
    int rg = tid >> 5;
    int c0 = cg * 4, r0 = rg * 4;

    {
        float4 b4 = *(const float4*)(bp + c0);
        float a00=b4.x,a01=b4.y,a02=b4.z,a03=b4.w;
        float a10=b4.x,a11=b4.y,a12=b4.z,a13=b4.w;
        float a20=b4.x,a21=b4.y,a22=b4.z,a23=b4.w;
        float a30=b4.x,a31=b4.y,a32=b4.z,a33=b4.w;
        for (int k = 0; k < IN_DIM; ++k) {
            float4 w = *(const float4*)(Wp + (size_t)k * HID + c0);
            float x0 = xt[r0 + 0][k], x1 = xt[r0 + 1][k];
            float x2 = xt[r0 + 2][k], x3 = xt[r0 + 3][k];
            a00 += x0*w.x; a01 += x0*w.y; a02 += x0*w.z; a03 += x0*w.w;
            a10 += x1*w.x; a11 += x1*w.y; a12 += x1*w.z; a13 += x1*w.w;
            a20 += x2*w.x; a21 += x2*w.y; a22 += x2*w.z; a23 += x2*w.w;
            a30 += x3*w.x; a31 += x3*w.y; a32 += x3*w.z; a33 += x3*w.w;
        }
        ht[r0+0][c0+0]=fmaxf(a00,0.f); ht[r0+0][c0+1]=fmaxf(a01,0.f);
        ht[r0+0][c0+2]=fmaxf(a02,0.f); ht[r0+0][c0+3]=fmaxf(a03,0.f);
        ht[r0+1][c0+0]=fmaxf(a10,0.f); ht[r0+1][c0+1]=fmaxf(a11,0.f);
        ht[r0+1][c0+2]=fmaxf(a12,0.f); ht[r0+1][c0+3]=fmaxf(a13,0.f);
        ht[r0+2][c0+0]=fmaxf(a20,0.f); ht[r0+2][c0+1]=fmaxf(a21,0.f);
        ht[r0+2][c0+2]=fmaxf(a22,0.f); ht[r0+2][c0+3]=fmaxf(a23,0.f);
        ht[r0+3][c0+0]=fmaxf(a30,0.f); ht[r0+3][c0+1]=fmaxf(a31,0.f);
        ht[r0+3][c0+2]=fmaxf(a32,0.f); ht[r0+3][c0+3]=fmaxf(a33,0.f);
    }
    __syncthreads();

    float a00=0,a01=0,a02=0,a03=0, a10=0,a11=0,a12=0,a13=0;
    float a20=0,a21=0,a22=0,a23=0, a30=0,a31=0,a32=0,a33=0;
    for (int k = 0; k < HID; ++k) {
        float4 w = *(const float4*)(Wg + (size_t)k * HID + c0);
        float h0 = ht[r0 + 0][k], h1 = ht[r0 + 1][k];
        float h2 = ht[r0 + 2][k], h3 = ht[r0 + 3][k];
        a00 += h0*w.x; a01 += h0*w.y; a02 += h0*w.z; a03 += h0*w.w;
        a10 += h1*w.x; a11 += h1*w.y; a12 += h1*w.z; a13 += h1*w.w;
        a20 += h2*w.x; a21 += h2*w.y; a22 += h2*w.z; a23 += h2*w.w;
        a30 += h3*w.x; a31 += h3*w.y; a32 += h3*w.z; a33 += h3*w.w;
    }
    {
        float4 v;
        v.x=a00; v.y=a01; v.z=a02; v.w=a03;
        *(float4*)(xh + (size_t)(row0 + r0 + 0) * HID + c0) = v;
        v.x=a10; v.y=a11; v.z=a12; v.w=a13;
        *(float4*)(xh + (size_t)(row0 + r0 + 1) * HID + c0) = v;
        v.x=a20; v.y=a21; v.z=a22; v.w=a23;
        *(float4*)(xh + (size_t)(row0 + r0 + 2) * HID + c0) = v;
        v.x=a30; v.y=a31; v.z=a32; v.w=a33;
        *(float4*)(xh + (size_t)(row0 + r0 + 3) * HID + c0) = v;
    }
    __syncthreads();
    ht[r0+0][c0+0]=a00; ht[r0+0][c0+1]=a01; ht[r0+0][c0+2]=a02; ht[r0+0][c0+3]=a03;
    ht[r0+1][c0+0]=a10; ht[r0+1][c0+1]=a11; ht[r0+1][c0+2]=a12; ht[r0+1][c0+3]=a13;
    ht[r0+2][c0+0]=a20; ht[r0+2][c0+1]=a21; ht[r0+2][c0+2]=a22; ht[r0+2][c0+3]=a23;
    ht[r0+3][c0+0]=a30; ht[r0+3][c0+1]=a31; ht[r0+3][c0+2]=a32; ht[r0+3][c0+3]=a33;
    __syncthreads();

    {
        int r = tid >> 3, hh = tid & 7;
        float s1 = 0.0f, s2 = 0.0f;
        #pragma unroll
        for (int d = 0; d < D; ++d) {
            float v = ht[r][hh * D + d];
            s1 += v * asrc[hh * D + d];
            s2 += v * adst[hh * D + d];
        }
        a_s[(size_t)(row0 + r) * H + hh] = s1;
        a_d[(size_t)(row0 + r) * H + hh] = s2;
    }
}

// transpose W_qkv (384x128 -> 128x384) and W_o (128x128 -> 128x128)
__global__ void k_tr(const float* __restrict__ W_qkv, const float* __restrict__ W_o,
                     float* __restrict__ WTq, float* __restrict__ WoT) {
    int idx = blockIdx.x * 256 + threadIdx.x;
    if (idx < 384 * 128) {
        int j = idx >> 7, c = idx & 127;
        WTq[c * 384 + j] = W_qkv[idx];
    } else if (idx < 384 * 128 + 128 * 128) {
        int r = idx - 384 * 128;
        int j = r >> 7, k = r & 127;
        WoT[k * 128 + j] = W_o[r];
    }
}

__device__ __forceinline__ void esd_g(const int* __restrict__ ei, int t, int i,
                                      int& s, int& d) {
    if (i < E) {
        s = ei[(size_t)(2 * t) * E + i];
        d = ei[(size_t)(2 * t + 1) * E + i];
    } else {
        s = d = i - E;
    }
}

__global__ void k_hist(const int* __restrict__ ei, int* __restrict__ cursor) {
    int idx = blockIdx.x * 256 + threadIdx.x;
    if (idx >= T * EN) return;
    int t = idx / EN;
    int i = idx - t * EN;
    int s, d;
    esd_g(ei, t, i, s, d);
    atomicAdd(&cursor[t * N + d], 1);
}

__global__ void k_scan(int* __restrict__ cursor, int* __restrict__ offs) {
    __shared__ int part[256];
    int t = blockIdx.x;
    int tid = threadIdx.x;
    const int CH = 20;
    int begin = tid * CH;
    int sum = 0;
    for (int k = 0; k < CH; ++k) {
        int i = begin + k;
        if (i < N) sum += cursor[t * N + i];
    }
    part[tid] = sum;
    __syncthreads();
    if (tid == 0) {
        int run = 0;
        for (int i = 0; i < 256; ++i) { int v = part[i]; part[i] = run; run += v; }
        offs[t * (N + 1) + N] = run;
    }
    __syncthreads();
    int run = part[tid];
    for (int k = 0; k < CH; ++k) {
        int i = begin + k;
        if (i < N) {
            int cnt = cursor[t * N + i];
            offs[t * (N + 1) + i] = run;
            cursor[t * N + i] = run;
            run += cnt;
        }
    }
}

__global__ void k_scatter(const int* __restrict__ ei, int* __restrict__ cursor,
                          int* __restrict__ csr_src) {
    int idx = blockIdx.x * 256 + threadIdx.x;
    if (idx >= T * EN) return;
    int t = idx / EN;
    int i = idx - t * EN;
    int s, d;
    esd_g(ei, t, i, s, d);
    int pos = atomicAdd(&cursor[t * N + d], 1);
    csr_src[(size_t)t * EN + pos] = s;
}

// GAT softmax + aggregation, one block per (t,dst), atomic-free
__global__ __launch_bounds__(128) void k_aggc(
        const int* __restrict__ offs, const int* __restrict__ csr_src,
        const float* __restrict__ a_s, const float* __restrict__ a_d,
        const float* __restrict__ xh, float* __restrict__ gout) {
    int b = blockIdx.x;
    int t = b / N;
    int dst = b - t * N;
    int tid = threadIdx.x;

    int o0 = offs[t * (N + 1) + dst];
    int o1 = offs[t * (N + 1) + dst + 1];
    int deg = o1 - o0;
    const int* esrc = csr_src + (size_t)t * EN + o0;
    const float* as_b = a_s + (size_t)t * N * H;
    const float* ad_b = a_d + (size_t)t * N * H;
    const float* xh_b = xh + (size_t)t * N * HID;

    __shared__ float lm[H][16], ls[H][16];
    __shared__ float fm[H], finv[H];
    __shared__ float lal[16][H];
    __shared__ int   lsrc[16];

    {
        int ha = tid & 7, l = tid >> 3;
        float ad_h = ad_b[dst * H + ha];
        float m = -1e30f, ssum = 0.0f;
        for (int i = l; i < deg; i += 16) {
            int src = esrc[i];
            float e = leaky(as_b[src * H + ha] + ad_h);
            if (e > m) { ssum = ssum * expf(m - e) + 1.0f; m = e; }
            else       { ssum += expf(e - m); }
        }
        lm[ha][l] = m;
        ls[ha][l] = ssum;
    }
    __syncthreads();
    if (tid < H) {
        float mm = -1e30f;
        for (int l = 0; l < 16; ++l) mm = fmaxf(mm, lm[tid][l]);
        float ss = 0.0f;
        for (int l = 0; l < 16; ++l) ss += ls[tid][l] * expf(lm[tid][l] - mm);
        fm[tid] = mm;
        finv[tid] = 1.0f / (ss + 1e-16f);
    }
    __syncthreads();

    int h = tid >> 4;
    int eh_e = tid >> 3, eh_h = tid & 7;
    float acc = 0.0f;
    for (int base = 0; base < deg; base += 16) {
        int ej = base + eh_e;
        if (ej < deg) {
            int src = esrc[ej];
            if (eh_h == 0) lsrc[eh_e] = src;
            float e = leaky(as_b[src * H + eh_h] + ad_b[dst * H + eh_h]);
            lal[eh_e][eh_h] = expf(e - fm[eh_h]) * finv[eh_h];
        }
        __syncthreads();
        int lim = min(16, deg - base);
        for (int j = 0; j < lim; ++j)
            acc += lal[j][h] * xh_b[(size_t)lsrc[j] * HID + tid];
        __syncthreads();
    }
    gout[(size_t)b * HID + tid] = acc;
}

// per-block: NBN nodes. LN1 -> fused q|k|v GEMM with 4x weight reuse ->
// in-register attention (shfl-reduced scores, no kl/vl LDS) -> W_o ->
// LN2 (shfl) -> emb(+div+noise) -> out
__global__ __launch_bounds__(128) void k_node(
        const float* __restrict__ gout, const float* __restrict__ b_gat,
        const float* __restrict__ g1, const float* __restrict__ be1,
        const float* __restrict__ WTq, const float* __restrict__ b_qkv,
        const float* __restrict__ WoT, const float* __restrict__ b_o,
        const float* __restrict__ g2, const float* __restrict__ be2,
        const float* __restrict__ noise, float* __restrict__ out) {
    // +4 pad breaks the 128-word row alias for the strided LN1 stat reads
    __shared__ float nrm[NBN][T][HID + 4];
    __shared__ float xlast[NBN][HID];
    __shared__ float ta_l[NBN][HID];
    __shared__ float mu1[NBN][T], rs1[NBN][T];
    __shared__ float red2[2][NBN][2];

    int n0 = blockIdx.x * NBN;
    int tid = threadIdx.x;

    // load gout + b_gat (raw pre-LN values)
    for (int i = tid; i < NBN * T * 32; i += 128) {
        int u = i >> 8, t = (i >> 5) & 7, c4 = i & 31;
        float4 g4 = *(const float4*)(gout + (size_t)(t * N + n0 + u) * HID + c4 * 4);
        float4 b4 = *(const float4*)(b_gat + c4 * 4);
        g4.x += b4.x; g4.y += b4.y; g4.z += b4.z; g4.w += b4.w;
        *(float4*)&nrm[u][t][c4 * 4] = g4;
    }
    __syncthreads();

    // LN1 stats: 32 rows x 4 lanes
    {
        int r = tid >> 2, j = tid & 3;
        int u = r >> 3, t = r & 7;
        float p = 0.0f;
        #pragma unroll
        for (int k = 0; k < 8; ++k) {
            float4 v4 = *(const float4*)&nrm[u][t][j * 32 + 4 * k];
            p += v4.x + v4.y + v4.z + v4.w;
        }
        p += __shfl_xor(p, 1); p += __shfl_xor(p, 2);
        float mu = p * (1.0f / HID);
        float vv = 0.0f;
        #pragma unroll
        for (int k = 0; k < 8; ++k) {
            float4 v4 = *(const float4*)&nrm[u][t][j * 32 + 4 * k];
            float dx = v4.x - mu, dy = v4.y - mu, dz = v4.z - mu, dw = v4.w - mu;
            vv += dx * dx + dy * dy + dz * dz + dw * dw;
        }
        vv += __shfl_xor(vv, 1); vv += __shfl_xor(vv, 2);
        if (j == 0) { mu1[u][t] = mu; rs1[u][t] = rsqrtf(vv * (1.0f / HID) + 1e-5f); }
    }
    __syncthreads();

    // normalize in place, saving raw last row for the residual
    for (int i = tid; i < NBN * T * 32; i += 128) {
        int u = i >> 8, t = (i >> 5) & 7, c4 = i & 31;
        float4 v4 = *(const float4*)&nrm[u][t][c4 * 4];
        if (t == T - 1) *(float4*)&xlast[u][c4 * 4] = v4;
        float mu = mu1[u][t], rs = rs1[u][t];
        float4 gg = *(const float4*)(g1 + c4 * 4);
        float4 bb = *(const float4*)(be1 + c4 * 4);
        v4.x = (v4.x - mu) * rs * gg.x + bb.x;
        v4.y = (v4.y - mu) * rs * gg.y + bb.y;
        v4.z = (v4.z - mu) * rs * gg.z + bb.z;
        v4.w = (v4.w - mu) * rs * gg.w + bb.w;
        *(float4*)&nrm[u][t][c4 * 4] = v4;
    }
    __syncthreads();

    // fused q|k|v GEMM: thread owns cols {tid, 128+tid, 256+tid};
    // each weight load feeds NBN*T (k,v) / NBN (q) FMAs
    float ka[NBN][T], va[NBN][T], qa[NBN];
    {
        float bq = b_qkv[tid], bk = b_qkv[HID + tid], bv = b_qkv[2 * HID + tid];
        #pragma unroll
        for (int u = 0; u < NBN; ++u) {
            qa[u] = bq;
            #pragma unroll
            for (int t = 0; t < T; ++t) { ka[u][t] = bk; va[u][t] = bv; }
        }
        const float* Wq = WTq + tid;
        const float* Wk = WTq + HID + tid;
        const float* Wv = WTq + 2 * HID + tid;

        float wq0[4], wk0[4], wv0[4], wq1[4], wk1[4], wv1[4];
        #pragma unroll
        for (int i = 0; i < 4; ++i) {
            wq0[i] = Wq[(size_t)i * 384];
            wk0[i] = Wk[(size_t)i * 384];
            wv0[i] = Wv[(size_t)i * 384];
        }
        for (int c = 0; c < HID; c += 8) {
            #pragma unroll
            for (int i = 0; i < 4; ++i) {
                wq1[i] = Wq[(size_t)(c + 4 + i) * 384];
                wk1[i] = Wk[(size_t)(c + 4 + i) * 384];
                wv1[i] = Wv[(size_t)(c + 4 + i) * 384];
            }
            #pragma unroll
            for (int u = 0; u < NBN; ++u) {
                #pragma unroll
                for (int t = 0; t < T; ++t) {
                    float4 nv = *(const float4*)&nrm[u][t][c];
                    ka[u][t] += nv.x*wk0[0] + nv.y*wk0[1] + nv.z*wk0[2] + nv.w*wk0[3];
                    va[u][t] += nv.x*wv0[0] + nv.y*wv0[1] + nv.z*wv0[2] + nv.w*wv0[3];
                    if (t == T - 1)
                        qa[u] += nv.x*wq0[0] + nv.y*wq0[1] + nv.z*wq0[2] + nv.w*wq0[3];
                }
            }
            if (c + 8 < HID) {
                #pragma unroll
                for (int i = 0; i < 4; ++i) {
                    wq0[i] = Wq[(size_t)(c + 8 + i) * 384];
                    wk0[i] = Wk[(size_t)(c + 8 + i) * 384];
                    wv0[i] = Wv[(size_t)(c + 8 + i) * 384];
                }
            }
            #pragma unroll
            for (int u = 0; u < NBN; ++u) {
                #pragma unroll
                for (int t = 0; t < T; ++t) {
                    float4 nv = *(const float4*)&nrm[u][t][c + 4];
                    ka[u][t] += nv.x*wk1[0] + nv.y*wk1[1] + nv.z*wk1[2] + nv.w*wk1[3];
                    va[u][t] += nv.x*wv1[0] + nv.y*wv1[1] + nv.z*wv1[2] + nv.w*wv1[3];
                    if (t == T - 1)
                        qa[u] += nv.x*wq1[0] + nv.y*wq1[1] + nv.z*wq1[2] + nv.w*wq1[3];
                }
            }
        }
    }

    // attention fully in registers: head group = 16 contiguous lanes
    // (heads never span a wave: lanes 0-63 = heads 0-3, 64-127 = heads 4-7)
    #pragma unroll
    for (int u = 0; u < NBN; ++u) {
        float sc[T];
        float mx = -1e30f;
        #pragma unroll
        for (int t = 0; t < T; ++t) {
            float p = qa[u] * ka[u][t];
            p += __shfl_xor(p, 1); p += __shfl_xor(p, 2);
            p += __shfl_xor(p, 4); p += __shfl_xor(p, 8);
            p *= 0.25f;               // 1/sqrt(D)
            sc[t] = p;
            mx = fmaxf(mx, p);
        }
        float ssum = 0.0f;
        #pragma unroll
        for (int t = 0; t < T; ++t) { sc[t] = expf(sc[t] - mx); ssum += sc[t]; }
        float inv = 1.0f / ssum;
        float acc = 0.0f;
        #pragma unroll
        for (int t = 0; t < T; ++t) acc += sc[t] * va[u][t];
        ta_l[u][tid] = acc * inv;
    }
    __syncthreads();

    // W_o (weights reused across NBN nodes) + residual
    float o[NBN];
    {
        float bo = b_o[tid];
        #pragma unroll
        for (int u = 0; u < NBN; ++u) o[u] = bo;
        for (int k = 0; k < HID; k += 4) {
            float w0 = WoT[(size_t)(k + 0) * HID + tid];
            float w1 = WoT[(size_t)(k + 1) * HID + tid];
            float w2 = WoT[(size_t)(k + 2) * HID + tid];
            float w3 = WoT[(size_t)(k + 3) * HID + tid];
            #pragma unroll
            for (int u = 0; u < NBN; ++u) {
                float4 t4 = *(const float4*)&ta_l[u][k];
                o[u] += t4.x * w0 + t4.y * w1 + t4.z * w2 + t4.w * w3;
            }
        }
    }

    // LN2 via shuffles (sum & sumsq in one pass) + epilogue
    float x2[NBN];
    #pragma unroll
    for (int u = 0; u < NBN; ++u) x2[u] = xlast[u][tid] + o[u];

    int wid = tid >> 6, lid = tid & 63;
    #pragma unroll
    for (int u = 0; u < NBN; ++u) {
        float s = x2[u], qv = x2[u] * x2[u];
        #pragma unroll
        for (int m = 1; m < 64; m <<= 1) {
            s += __shfl_xor(s, m);
            qv += __shfl_xor(qv, m);
        }
        if (lid == 0) { red2[wid][u][0] = s; red2[wid][u][1] = qv; }
    }
    __syncthreads();

    float gg = g2[tid], bb = be2[tid];
    #pragma unroll
    for (int u = 0; u < NBN; ++u) {
        float s  = red2[0][u][0] + red2[1][u][0];
        float qv = red2[0][u][1] + red2[1][u][1];
        float mu = s * (1.0f / HID);
        float var = qv * (1.0f / HID) - mu * mu;
        float rstd = rsqrtf(var + 1e-5f);
        int n = n0 + u;
        float div = sinf(((float)n / (float)N) * 6.28f) * 0.1f;
        out[(size_t)n * HID + tid] = (x2[u] - mu) * rstd * gg + bb + div
                                   + noise[(size_t)n * HID + tid] * 0.05f;
    }
}

// classifier: tiled h1 = emb@Wc1 + bc1 -> LN3 -> gelu -> logits
__global__ __launch_bounds__(256) void k_cls(const float* __restrict__ emb,
                                             const float* __restrict__ Wc1,
                                             const float* __restrict__ bc1,
                                             const float* __restrict__ gc,
                                             const float* __restrict__ bec,
                                             const float* __restrict__ Wc2,
                                             const float* __restrict__ bc2,
                                             float* __restrict__ out) {
    __shared__ float et[MT][HID];
    __shared__ float h1t[MT][HID + 1];
    int row0 = blockIdx.x * MT;
    int tid = threadIdx.x;

    for (int idx = tid; idx < MT * HID; idx += 256) {
        int r = idx >> 7, c = idx & 127;
        int row = row0 + r;
        et[r][c] = (row < N) ? emb[(size_t)row * HID + c] : 0.0f;
    }
    __syncthreads();

    {
        int cg = tid & 31, rg = tid >> 5;
        int c0 = cg * 4, r0 = rg * 4;
        float4 b4 = *(const float4*)(bc1 + c0);
        float a00=b4.x,a01=b4.y,a02=b4.z,a03=b4.w;
        float a10=b4.x,a11=b4.y,a12=b4.z,a13=b4.w;
        float a20=b4.x,a21=b4.y,a22=b4.z,a23=b4.w;
        float a30=b4.x,a31=b4.y,a32=b4.z,a33=b4.w;
        for (int k = 0; k < HID; ++k) {
            float4 w = *(const float4*)(Wc1 + (size_t)k * HID + c0);
            float e0 = et[r0 + 0][k], e1 = et[r0 + 1][k];
            float e2 = et[r0 + 2][k], e3 = et[r0 + 3][k];
            a00 += e0*w.x; a01 += e0*w.y; a02 += e0*w.z; a03 += e0*w.w;
            a10 += e1*w.x; a11 += e1*w.y; a12 += e1*w.z; a13 += e1*w.w;
            a20 += e2*w.x; a21 += e2*w.y; a22 += e2*w.z; a23 += e2*w.w;
            a30 += e3*w.x; a31 += e3*w.y; a32 += e3*w.z; a33 += e3*w.w;
        }
        h1t[r0+0][c0+0]=a00; h1t[r0+0][c0+1]=a01; h1t[r0+0][c0+2]=a02; h1t[r0+0][c0+3]=a03;
        h1t[r0+1][c0+0]=a10; h1t[r0+1][c0+1]=a11; h1t[r0+1][c0+2]=a12; h1t[r0+1][c0+3]=a13;
        h1t[r0+2][c0+0]=a20; h1t[r0+2][c0+1]=a21; h1t[r0+2][c0+2]=a22; h1t[r0+2][c0+3]=a23;
        h1t[r0+3][c0+0]=a30; h1t[r0+3][c0+1]=a31; h1t[r0+3][c0+2]=a32; h1t[r0+3][c0+3]=a33;
    }
    __syncthreads();

    // LN3 + gelu: 8 lanes per row (32 rows x 8 = 256 threads)
    {
        int r = tid >> 3, l = tid & 7;
        float p = 0.0f;
        #pragma unroll
        for (int k = 0; k < 16; ++k) p += h1t[r][l + 8 * k];
        #pragma unroll
        for (int m = 1; m < 8; m <<= 1) p += __shfl_xor(p, m);
        float mu = p * (1.0f / HID);
        float v = 0.0f;
        #pragma unroll
        for (int k = 0; k < 16; ++k) { float d = h1t[r][l + 8 * k] - mu; v += d * d; }
        #pragma unroll
        for (int m = 1; m < 8; m <<= 1) v += __shfl_xor(v, m);
        float rstd = rsqrtf(v * (1.0f / HID) + 1e-5f);
        #pragma unroll
        for (int k = 0; k < 16; ++k) {
            int c = l + 8 * k;
            float lnv = (h1t[r][c] - mu) * rstd * gc[c] + bec[c];
            h1t[r][c] = 0.5f * lnv * (1.0f + erff(lnv * 0.70710678118f));
        }
    }
    __syncthreads();

    // logits: 64 outputs (32 rows x 2)
    if (tid < MT * NC) {
        int r = tid >> 1, j = tid & 1;
        int row = row0 + r;
        if (row < N) {
            float acc = bc2[j];
            #pragma unroll 8
            for (int c = 0; c < HID; ++c) acc += h1t[r][c] * Wc2[c * NC + j];
            if (j == 1) acc += sinf((float)row * 0.5f) * 0.2f;
            out[(size_t)N * HID + (size_t)row * NC + j] = acc;
        }
    }
}

extern "C" void kernel_launch(void* const* d_in, const int* in_sizes, int n_in,
                              void* d_out, int out_size, void* d_ws, size_t ws_size,
                              hipStream_t stream) {
    const float* x      = (const float*)d_in[0];
    const int*   ei     = (const int*)d_in[1];
    const float* noise  = (const float*)d_in[2];
    const float* W_proj = (const float*)d_in[3];
    const float* b_proj = (const float*)d_in[4];
    const float* W_gat  = (const float*)d_in[5];
    const float* a_src  = (const float*)d_in[6];
    const float* a_dst  = (const float*)d_in[7];
    const float* b_gat  = (const float*)d_in[8];
    const float* g1     = (const float*)d_in[9];
    const float* be1    = (const float*)d_in[10];
    const float* W_qkv  = (const float*)d_in[11];
    const float* b_qkv  = (const float*)d_in[12];
    const float* W_o    = (const float*)d_in[13];
    const float* b_o    = (const float*)d_in[14];
    const float* g2     = (const float*)d_in[15];
    const float* be2    = (const float*)d_in[16];
    const float* Wc1    = (const float*)d_in[17];
    const float* bc1    = (const float*)d_in[18];
    const float* gc     = (const float*)d_in[19];
    const float* bec    = (const float*)d_in[20];
    const float* Wc2    = (const float*)d_in[21];
    const float* bc2    = (const float*)d_in[22];
    float* out = (float*)d_out;

    float* xh    = (float*)d_ws;                 // 5,120,000
    float* gout  = xh + 5120000;                 // 5,120,000
    float* a_s   = gout + 5120000;               //   320,000
    float* a_d   = a_s + 320000;                 //   320,000
    int*   offs    = (int*)(a_d + 320000);       //    40,008
    int*   cursor  = offs + 40008;               //    40,000
    int*   csr_src = cursor + 40000;             // 1,320,000
    float* WTq   = (float*)(csr_src + 1320000);  //    49,152
    float* WoT   = WTq + 49152;                  //    16,384

    k_tr<<<(384 * 128 + 128 * 128 + 255) / 256, 256, 0, stream>>>(W_qkv, W_o, WTq, WoT);

    k_pg<<<T * N / MT, 256, 0, stream>>>(x, W_proj, b_proj, W_gat, a_src, a_dst,
                                         xh, a_s, a_d);

    hipMemsetAsync(cursor, 0, 40000 * sizeof(int), stream);
    k_hist<<<(T * EN + 255) / 256, 256, 0, stream>>>(ei, cursor);
    k_scan<<<T, 256, 0, stream>>>(cursor, offs);
    k_scatter<<<(T * EN + 255) / 256, 256, 0, stream>>>(ei, cursor, csr_src);

    k_aggc<<<T * N, 128, 0, stream>>>(offs, csr_src, a_s, a_d, xh, gout);

    k_node<<<N / NBN, 128, 0, stream>>>(gout, b_gat, g1, be1, WTq, b_qkv, WoT, b_o,
                                        g2, be2, noise, out);

    k_cls<<<(N + MT - 1) / MT, 256, 0, stream>>>(out, Wc1, bc1, gc, bec, Wc2, bc2, out);
}

// Round 2
// 462.342 us; speedup vs baseline: 1.1347x; 1.1347x over previous
//
#include <hip/hip_runtime.h>
#include <math.h>

#define T 8
#define N 5000
#define E 160000
#define EN (E + N)
#define IN_DIM 64
#define HID 128
#define H 8
#define D 16
#define NC 2
#define MT 32            // rows per k_pg / k_cls block

__device__ __forceinline__ float leaky(float e) { return (e >= 0.0f) ? e : 0.2f * e; }

// fused h=relu(x@Wp+bp); xh=h@Wg; a_s/a_d coef epilogue
__global__ __launch_bounds__(256) void k_pg(const float* __restrict__ x,
                                            const float* __restrict__ Wp,
                                            const float* __restrict__ bp,
                                            const float* __restrict__ Wg,
                                            const float* __restrict__ asrc,
                                            const float* __restrict__ adst,
                                            float* __restrict__ xh,
                                            float* __restrict__ a_s,
                                            float* __restrict__ a_d) {
    __shared__ float xt[MT][IN_DIM];
    __shared__ float ht[MT][HID + 1];
    int row0 = blockIdx.x * MT;
    int tid = threadIdx.x;

    for (int idx = tid; idx < MT * IN_DIM; idx += 256) {
        int r = idx >> 6, k = idx & 63;
        xt[r][k] = x[(size_t)(row0 + r) * IN_DIM + k];
    }
    __syncthreads();

    int cg = tid & 31;
    int rg = tid >> 5;
    int c0 = cg * 4, r0 = rg * 4;

    {
        float4 b4 = *(const float4*)(bp + c0);
        float a00=b4.x,a01=b4.y,a02=b4.z,a03=b4.w;
        float a10=b4.x,a11=b4.y,a12=b4.z,a13=b4.w;
        float a20=b4.x,a21=b4.y,a22=b4.z,a23=b4.w;
        float a30=b4.x,a31=b4.y,a32=b4.z,a33=b4.w;
        for (int k = 0; k < IN_DIM; ++k) {
            float4 w = *(const float4*)(Wp + (size_t)k * HID + c0);
            float x0 = xt[r0 + 0][k], x1 = xt[r0 + 1][k];
            float x2 = xt[r0 + 2][k], x3 = xt[r0 + 3][k];
            a00 += x0*w.x; a01 += x0*w.y; a02 += x0*w.z; a03 += x0*w.w;
            a10 += x1*w.x; a11 += x1*w.y; a12 += x1*w.z; a13 += x1*w.w;
            a20 += x2*w.x; a21 += x2*w.y; a22 += x2*w.z; a23 += x2*w.w;
            a30 += x3*w.x; a31 += x3*w.y; a32 += x3*w.z; a33 += x3*w.w;
        }
        ht[r0+0][c0+0]=fmaxf(a00,0.f); ht[r0+0][c0+1]=fmaxf(a01,0.f);
        ht[r0+0][c0+2]=fmaxf(a02,0.f); ht[r0+0][c0+3]=fmaxf(a03,0.f);
        ht[r0+1][c0+0]=fmaxf(a10,0.f); ht[r0+1][c0+1]=fmaxf(a11,0.f);
        ht[r0+1][c0+2]=fmaxf(a12,0.f); ht[r0+1][c0+3]=fmaxf(a13,0.f);
        ht[r0+2][c0+0]=fmaxf(a20,0.f); ht[r0+2][c0+1]=fmaxf(a21,0.f);
        ht[r0+2][c0+2]=fmaxf(a22,0.f); ht[r0+2][c0+3]=fmaxf(a23,0.f);
        ht[r0+3][c0+0]=fmaxf(a30,0.f); ht[r0+3][c0+1]=fmaxf(a31,0.f);
        ht[r0+3][c0+2]=fmaxf(a32,0.f); ht[r0+3][c0+3]=fmaxf(a33,0.f);
    }
    __syncthreads();

    float a00=0,a01=0,a02=0,a03=0, a10=0,a11=0,a12=0,a13=0;
    float a20=0,a21=0,a22=0,a23=0, a30=0,a31=0,a32=0,a33=0;
    for (int k = 0; k < HID; ++k) {
        float4 w = *(const float4*)(Wg + (size_t)k * HID + c0);
        float h0 = ht[r0 + 0][k], h1 = ht[r0 + 1][k];
        float h2 = ht[r0 + 2][k], h3 = ht[r0 + 3][k];
        a00 += h0*w.x; a01 += h0*w.y; a02 += h0*w.z; a03 += h0*w.w;
        a10 += h1*w.x; a11 += h1*w.y; a12 += h1*w.z; a13 += h1*w.w;
        a20 += h2*w.x; a21 += h2*w.y; a22 += h2*w.z; a23 += h2*w.w;
        a30 += h3*w.x; a31 += h3*w.y; a32 += h3*w.z; a33 += h3*w.w;
    }
    {
        float4 v;
        v.x=a00; v.y=a01; v.z=a02; v.w=a03;
        *(float4*)(xh + (size_t)(row0 + r0 + 0) * HID + c0) = v;
        v.x=a10; v.y=a11; v.z=a12; v.w=a13;
        *(float4*)(xh + (size_t)(row0 + r0 + 1) * HID + c0) = v;
        v.x=a20; v.y=a21; v.z=a22; v.w=a23;
        *(float4*)(xh + (size_t)(row0 + r0 + 2) * HID + c0) = v;
        v.x=a30; v.y=a31; v.z=a32; v.w=a33;
        *(float4*)(xh + (size_t)(row0 + r0 + 3) * HID + c0) = v;
    }
    __syncthreads();
    ht[r0+0][c0+0]=a00; ht[r0+0][c0+1]=a01; ht[r0+0][c0+2]=a02; ht[r0+0][c0+3]=a03;
    ht[r0+1][c0+0]=a10; ht[r0+1][c0+1]=a11; ht[r0+1][c0+2]=a12; ht[r0+1][c0+3]=a13;
    ht[r0+2][c0+0]=a20; ht[r0+2][c0+1]=a21; ht[r0+2][c0+2]=a22; ht[r0+2][c0+3]=a23;
    ht[r0+3][c0+0]=a30; ht[r0+3][c0+1]=a31; ht[r0+3][c0+2]=a32; ht[r0+3][c0+3]=a33;
    __syncthreads();

    {
        int r = tid >> 3, hh = tid & 7;
        float s1 = 0.0f, s2 = 0.0f;
        #pragma unroll
        for (int d = 0; d < D; ++d) {
            float v = ht[r][hh * D + d];
            s1 += v * asrc[hh * D + d];
            s2 += v * adst[hh * D + d];
        }
        a_s[(size_t)(row0 + r) * H + hh] = s1;
        a_d[(size_t)(row0 + r) * H + hh] = s2;
    }
}

// transpose W_qkv (384x128 -> 128x384) and W_o (128x128 -> 128x128)
__global__ void k_tr(const float* __restrict__ W_qkv, const float* __restrict__ W_o,
                     float* __restrict__ WTq, float* __restrict__ WoT) {
    int idx = blockIdx.x * 256 + threadIdx.x;
    if (idx < 384 * 128) {
        int j = idx >> 7, c = idx & 127;
        WTq[c * 384 + j] = W_qkv[idx];
    } else if (idx < 384 * 128 + 128 * 128) {
        int r = idx - 384 * 128;
        int j = r >> 7, k = r & 127;
        WoT[k * 128 + j] = W_o[r];
    }
}

__device__ __forceinline__ void esd_g(const int* __restrict__ ei, int t, int i,
                                      int& s, int& d) {
    if (i < E) {
        s = ei[(size_t)(2 * t) * E + i];
        d = ei[(size_t)(2 * t + 1) * E + i];
    } else {
        s = d = i - E;
    }
}

__global__ void k_hist(const int* __restrict__ ei, int* __restrict__ cursor) {
    int idx = blockIdx.x * 256 + threadIdx.x;
    if (idx >= T * EN) return;
    int t = idx / EN;
    int i = idx - t * EN;
    int s, d;
    esd_g(ei, t, i, s, d);
    atomicAdd(&cursor[t * N + d], 1);
}

__global__ void k_scan(int* __restrict__ cursor, int* __restrict__ offs) {
    __shared__ int part[256];
    int t = blockIdx.x;
    int tid = threadIdx.x;
    const int CH = 20;
    int begin = tid * CH;
    int sum = 0;
    for (int k = 0; k < CH; ++k) {
        int i = begin + k;
        if (i < N) sum += cursor[t * N + i];
    }
    part[tid] = sum;
    __syncthreads();
    if (tid == 0) {
        int run = 0;
        for (int i = 0; i < 256; ++i) { int v = part[i]; part[i] = run; run += v; }
        offs[t * (N + 1) + N] = run;
    }
    __syncthreads();
    int run = part[tid];
    for (int k = 0; k < CH; ++k) {
        int i = begin + k;
        if (i < N) {
            int cnt = cursor[t * N + i];
            offs[t * (N + 1) + i] = run;
            cursor[t * N + i] = run;
            run += cnt;
        }
    }
}

__global__ void k_scatter(const int* __restrict__ ei, int* __restrict__ cursor,
                          int* __restrict__ csr_src) {
    int idx = blockIdx.x * 256 + threadIdx.x;
    if (idx >= T * EN) return;
    int t = idx / EN;
    int i = idx - t * EN;
    int s, d;
    esd_g(ei, t, i, s, d);
    int pos = atomicAdd(&cursor[t * N + d], 1);
    csr_src[(size_t)t * EN + pos] = s;
}

// GAT softmax + aggregation, one block per (dst,t), atomic-free.
// Block index encoded as dst*T + t so the 8 t-slices map to the 8 XCDs
// (consecutive blockIdx round-robin across XCDs): each XCD's L2 then only
// holds one t's xh slice (2.56 MB < 4 MB).
__global__ __launch_bounds__(128) void k_aggc(
        const int* __restrict__ offs, const int* __restrict__ csr_src,
        const float* __restrict__ a_s, const float* __restrict__ a_d,
        const float* __restrict__ xh, float* __restrict__ gout) {
    int b = blockIdx.x;
    int t = b & 7;            // T == 8
    int dst = b >> 3;
    int tid = threadIdx.x;

    int o0 = offs[t * (N + 1) + dst];
    int o1 = offs[t * (N + 1) + dst + 1];
    int deg = o1 - o0;
    const int* esrc = csr_src + (size_t)t * EN + o0;
    const float* as_b = a_s + (size_t)t * N * H;
    const float* ad_b = a_d + (size_t)t * N * H;
    const float* xh_b = xh + (size_t)t * N * HID;

    __shared__ float lm[H][16], ls[H][16];
    __shared__ float fm[H], finv[H];
    __shared__ float lal[16][H];
    __shared__ int   lsrc[16];

    {
        int ha = tid & 7, l = tid >> 3;
        float ad_h = ad_b[dst * H + ha];
        float m = -1e30f, ssum = 0.0f;
        for (int i = l; i < deg; i += 16) {
            int src = esrc[i];
            float e = leaky(as_b[src * H + ha] + ad_h);
            if (e > m) { ssum = ssum * expf(m - e) + 1.0f; m = e; }
            else       { ssum += expf(e - m); }
        }
        lm[ha][l] = m;
        ls[ha][l] = ssum;
    }
    __syncthreads();
    if (tid < H) {
        float mm = -1e30f;
        for (int l = 0; l < 16; ++l) mm = fmaxf(mm, lm[tid][l]);
        float ss = 0.0f;
        for (int l = 0; l < 16; ++l) ss += ls[tid][l] * expf(lm[tid][l] - mm);
        fm[tid] = mm;
        finv[tid] = 1.0f / (ss + 1e-16f);
    }
    __syncthreads();

    int h = tid >> 4;
    int eh_e = tid >> 3, eh_h = tid & 7;
    float adh_e = ad_b[dst * H + eh_h];
    float fm_e = fm[eh_h], finv_e = finv[eh_h];
    float acc = 0.0f;

    int full = deg & ~15;     // full 16-edge tiles
    int base = 0;
    for (; base < full; base += 16) {
        int src = esrc[base + eh_e];
        if (eh_h == 0) lsrc[eh_e] = src;
        float e = leaky(as_b[src * H + eh_h] + adh_e);
        lal[eh_e][eh_h] = expf(e - fm_e) * finv_e;
        __syncthreads();
        // compile-time bound: compiler can batch all 16 independent gathers
        #pragma unroll
        for (int j = 0; j < 16; j += 4) {
            float l0 = lal[j + 0][h], l1 = lal[j + 1][h];
            float l2 = lal[j + 2][h], l3 = lal[j + 3][h];
            int s0 = lsrc[j + 0], s1 = lsrc[j + 1];
            int s2 = lsrc[j + 2], s3 = lsrc[j + 3];
            float v0 = xh_b[(size_t)s0 * HID + tid];
            float v1 = xh_b[(size_t)s1 * HID + tid];
            float v2 = xh_b[(size_t)s2 * HID + tid];
            float v3 = xh_b[(size_t)s3 * HID + tid];
            acc += l0 * v0 + l1 * v1 + l2 * v2 + l3 * v3;
        }
        __syncthreads();
    }
    if (base < deg) {
        int ej = base + eh_e;
        if (ej < deg) {
            int src = esrc[ej];
            if (eh_h == 0) lsrc[eh_e] = src;
            float e = leaky(as_b[src * H + eh_h] + adh_e);
            lal[eh_e][eh_h] = expf(e - fm_e) * finv_e;
        }
        __syncthreads();
        int lim = deg - base;
        for (int j = 0; j < lim; ++j)
            acc += lal[j][h] * xh_b[(size_t)lsrc[j] * HID + tid];
        __syncthreads();
    }
    gout[(size_t)(t * N + dst) * HID + tid] = acc;
}

// per-node: LN1 -> fused k|v|q (pipelined weight prefetch) -> attention
// -> W_o -> LN2 -> emb(+div+noise) -> out
__global__ __launch_bounds__(128) void k_node(
        const float* __restrict__ gout, const float* __restrict__ b_gat,
        const float* __restrict__ g1, const float* __restrict__ be1,
        const float* __restrict__ WTq, const float* __restrict__ b_qkv,
        const float* __restrict__ WoT, const float* __restrict__ b_o,
        const float* __restrict__ g2, const float* __restrict__ be2,
        const float* __restrict__ noise, float* __restrict__ out) {
    __shared__ float nrm[T][HID];
    __shared__ float xlast[HID];
    __shared__ float ql[HID];
    __shared__ float kl[H][T][D];
    __shared__ float vl[H][T][D];
    __shared__ float attn_l[H][T];
    __shared__ float ta[HID];
    __shared__ float red[128];
    __shared__ float mu1[T], rs1[T];

    int n = blockIdx.x;
    int tid = threadIdx.x;

    for (int i = tid; i < T * HID; i += 128) {
        int t = i >> 7, c = i & 127;
        nrm[t][c] = gout[(size_t)(t * N + n) * HID + c] + b_gat[c];
    }
    __syncthreads();

    // LN1: 16 lanes per row
    {
        int row = tid >> 4, j = tid & 15;
        float p = 0.0f;
        #pragma unroll
        for (int k = 0; k < 8; ++k) p += nrm[row][j + 16 * k];
        #pragma unroll
        for (int m = 1; m < 16; m <<= 1) p += __shfl_xor(p, m);
        float mu = p * (1.0f / HID);
        float v = 0.0f;
        #pragma unroll
        for (int k = 0; k < 8; ++k) { float d = nrm[row][j + 16 * k] - mu; v += d * d; }
        #pragma unroll
        for (int m = 1; m < 16; m <<= 1) v += __shfl_xor(v, m);
        if (j == 0) { mu1[row] = mu; rs1[row] = rsqrtf(v * (1.0f / HID) + 1e-5f); }
    }
    __syncthreads();

    for (int i = tid; i < T * HID; i += 128) {
        int t = i >> 7, c = i & 127;
        float raw = nrm[t][c];
        if (t == T - 1) xlast[c] = raw;
        nrm[t][c] = (raw - mu1[t]) * rs1[t] * g1[c] + be1[c];
    }
    __syncthreads();

    // fused k|v|q GEMM, two-bank software-pipelined weight prefetch
    {
        int jk = HID + tid, jv = 2 * HID + tid;
        float ka[T], va[T];
        float bk = b_qkv[jk], bv = b_qkv[jv];
        #pragma unroll
        for (int tt = 0; tt < T; ++tt) { ka[tt] = bk; va[tt] = bv; }
        float qa = b_qkv[tid];

        float wk0[4], wv0[4], wq0[4], wk1[4], wv1[4], wq1[4];
        #pragma unroll
        for (int i = 0; i < 4; ++i) {
            wk0[i] = WTq[(size_t)i * 384 + jk];
            wv0[i] = WTq[(size_t)i * 384 + jv];
            wq0[i] = WTq[(size_t)i * 384 + tid];
        }
        for (int c = 0; c < HID; c += 8) {
            #pragma unroll
            for (int i = 0; i < 4; ++i) {
                wk1[i] = WTq[(size_t)(c + 4 + i) * 384 + jk];
                wv1[i] = WTq[(size_t)(c + 4 + i) * 384 + jv];
                wq1[i] = WTq[(size_t)(c + 4 + i) * 384 + tid];
            }
            #pragma unroll
            for (int tt = 0; tt < T; ++tt) {
                float4 nv = *(const float4*)&nrm[tt][c];
                ka[tt] += nv.x*wk0[0] + nv.y*wk0[1] + nv.z*wk0[2] + nv.w*wk0[3];
                va[tt] += nv.x*wv0[0] + nv.y*wv0[1] + nv.z*wv0[2] + nv.w*wv0[3];
                if (tt == T - 1)
                    qa += nv.x*wq0[0] + nv.y*wq0[1] + nv.z*wq0[2] + nv.w*wq0[3];
            }
            if (c + 8 < HID) {
                #pragma unroll
                for (int i = 0; i < 4; ++i) {
                    wk0[i] = WTq[(size_t)(c + 8 + i) * 384 + jk];
                    wv0[i] = WTq[(size_t)(c + 8 + i) * 384 + jv];
                    wq0[i] = WTq[(size_t)(c + 8 + i) * 384 + tid];
                }
            }
            #pragma unroll
            for (int tt = 0; tt < T; ++tt) {
                float4 nv = *(const float4*)&nrm[tt][c + 4];
                ka[tt] += nv.x*wk1[0] + nv.y*wk1[1] + nv.z*wk1[2] + nv.w*wk1[3];
                va[tt] += nv.x*wv1[0] + nv.y*wv1[1] + nv.z*wv1[2] + nv.w*wv1[3];
                if (tt == T - 1)
                    qa += nv.x*wq1[0] + nv.y*wq1[1] + nv.z*wq1[2] + nv.w*wq1[3];
            }
        }
        int hh = tid >> 4, dd = tid & 15;
        #pragma unroll
        for (int tt = 0; tt < T; ++tt) {
            kl[hh][tt][dd] = ka[tt];
            vl[hh][tt][dd] = va[tt];
        }
        ql[tid] = qa;
    }
    __syncthreads();

    if (tid < H) {
        int hh = tid;
        float sc[T];
        float mx = -1e30f;
        #pragma unroll
        for (int tk = 0; tk < T; ++tk) {
            float a = 0.0f;
            #pragma unroll
            for (int dd = 0; dd < D; ++dd) a += ql[hh * D + dd] * kl[hh][tk][dd];
            a *= 0.25f;
            sc[tk] = a;
            mx = fmaxf(mx, a);
        }
        float ssum = 0.0f;
        #pragma unroll
        for (int tk = 0; tk < T; ++tk) { sc[tk] = expf(sc[tk] - mx); ssum += sc[tk]; }
        float inv = 1.0f / ssum;
        #pragma unroll
        for (int tk = 0; tk < T; ++tk) attn_l[hh][tk] = sc[tk] * inv;
    }
    __syncthreads();

    {
        int hh = tid >> 4, dd = tid & 15;
        float a = 0.0f;
        #pragma unroll
        for (int tk = 0; tk < T; ++tk) a += attn_l[hh][tk] * vl[hh][tk][dd];
        ta[tid] = a;
    }
    __syncthreads();

    // W_o + residual
    float o = b_o[tid];
    #pragma unroll 8
    for (int k = 0; k < HID; k += 4) {
        float4 t4 = *(const float4*)&ta[k];
        o += t4.x * WoT[(size_t)(k + 0) * 128 + tid]
           + t4.y * WoT[(size_t)(k + 1) * 128 + tid]
           + t4.z * WoT[(size_t)(k + 2) * 128 + tid]
           + t4.w * WoT[(size_t)(k + 3) * 128 + tid];
    }
    float x2 = xlast[tid] + o;

    red[tid] = x2;
    __syncthreads();
    if (tid < 64) {
        float s = red[tid] + red[tid + 64];
        #pragma unroll
        for (int m = 1; m < 64; m <<= 1) s += __shfl_xor(s, m);
        if (tid == 0) red[0] = s;
    }
    __syncthreads();
    float mu2 = red[0] * (1.0f / HID);
    __syncthreads();
    float d2 = x2 - mu2;
    red[tid] = d2 * d2;
    __syncthreads();
    if (tid < 64) {
        float s = red[tid] + red[tid + 64];
        #pragma unroll
        for (int m = 1; m < 64; m <<= 1) s += __shfl_xor(s, m);
        if (tid == 0) red[0] = s;
    }
    __syncthreads();
    float rstd2 = rsqrtf(red[0] * (1.0f / HID) + 1e-5f);

    float div = sinf(((float)n / (float)N) * 6.28f) * 0.1f;
    float emb = d2 * rstd2 * g2[tid] + be2[tid]
              + div + noise[(size_t)n * HID + tid] * 0.05f;
    out[(size_t)n * HID + tid] = emb;
}

// classifier: tiled h1 = emb@Wc1 + bc1 -> LN3 -> gelu -> logits
__global__ __launch_bounds__(256) void k_cls(const float* __restrict__ emb,
                                             const float* __restrict__ Wc1,
                                             const float* __restrict__ bc1,
                                             const float* __restrict__ gc,
                                             const float* __restrict__ bec,
                                             const float* __restrict__ Wc2,
                                             const float* __restrict__ bc2,
                                             float* __restrict__ out) {
    __shared__ float et[MT][HID];
    __shared__ float h1t[MT][HID + 1];
    int row0 = blockIdx.x * MT;
    int tid = threadIdx.x;

    for (int idx = tid; idx < MT * HID; idx += 256) {
        int r = idx >> 7, c = idx & 127;
        int row = row0 + r;
        et[r][c] = (row < N) ? emb[(size_t)row * HID + c] : 0.0f;
    }
    __syncthreads();

    {
        int cg = tid & 31, rg = tid >> 5;
        int c0 = cg * 4, r0 = rg * 4;
        float4 b4 = *(const float4*)(bc1 + c0);
        float a00=b4.x,a01=b4.y,a02=b4.z,a03=b4.w;
        float a10=b4.x,a11=b4.y,a12=b4.z,a13=b4.w;
        float a20=b4.x,a21=b4.y,a22=b4.z,a23=b4.w;
        float a30=b4.x,a31=b4.y,a32=b4.z,a33=b4.w;
        for (int k = 0; k < HID; ++k) {
            float4 w = *(const float4*)(Wc1 + (size_t)k * HID + c0);
            float e0 = et[r0 + 0][k], e1 = et[r0 + 1][k];
            float e2 = et[r0 + 2][k], e3 = et[r0 + 3][k];
            a00 += e0*w.x; a01 += e0*w.y; a02 += e0*w.z; a03 += e0*w.w;
            a10 += e1*w.x; a11 += e1*w.y; a12 += e1*w.z; a13 += e1*w.w;
            a20 += e2*w.x; a21 += e2*w.y; a22 += e2*w.z; a23 += e2*w.w;
            a30 += e3*w.x; a31 += e3*w.y; a32 += e3*w.z; a33 += e3*w.w;
        }
        h1t[r0+0][c0+0]=a00; h1t[r0+0][c0+1]=a01; h1t[r0+0][c0+2]=a02; h1t[r0+0][c0+3]=a03;
        h1t[r0+1][c0+0]=a10; h1t[r0+1][c0+1]=a11; h1t[r0+1][c0+2]=a12; h1t[r0+1][c0+3]=a13;
        h1t[r0+2][c0+0]=a20; h1t[r0+2][c0+1]=a21; h1t[r0+2][c0+2]=a22; h1t[r0+2][c0+3]=a23;
        h1t[r0+3][c0+0]=a30; h1t[r0+3][c0+1]=a31; h1t[r0+3][c0+2]=a32; h1t[r0+3][c0+3]=a33;
    }
    __syncthreads();

    // LN3 + gelu: 8 lanes per row (32 rows x 8 = 256 threads)
    {
        int r = tid >> 3, l = tid & 7;
        float p = 0.0f;
        #pragma unroll
        for (int k = 0; k < 16; ++k) p += h1t[r][l + 8 * k];
        #pragma unroll
        for (int m = 1; m < 8; m <<= 1) p += __shfl_xor(p, m);
        float mu = p * (1.0f / HID);
        float v = 0.0f;
        #pragma unroll
        for (int k = 0; k < 16; ++k) { float d = h1t[r][l + 8 * k] - mu; v += d * d; }
        #pragma unroll
        for (int m = 1; m < 8; m <<= 1) v += __shfl_xor(v, m);
        float rstd = rsqrtf(v * (1.0f / HID) + 1e-5f);
        #pragma unroll
        for (int k = 0; k < 16; ++k) {
            int c = l + 8 * k;
            float lnv = (h1t[r][c] - mu) * rstd * gc[c] + bec[c];
            h1t[r][c] = 0.5f * lnv * (1.0f + erff(lnv * 0.70710678118f));
        }
    }
    __syncthreads();

    // logits: 64 outputs (32 rows x 2)
    if (tid < MT * NC) {
        int r = tid >> 1, j = tid & 1;
        int row = row0 + r;
        if (row < N) {
            float acc = bc2[j];
            #pragma unroll 8
            for (int c = 0; c < HID; ++c) acc += h1t[r][c] * Wc2[c * NC + j];
            if (j == 1) acc += sinf((float)row * 0.5f) * 0.2f;
            out[(size_t)N * HID + (size_t)row * NC + j] = acc;
        }
    }
}

extern "C" void kernel_launch(void* const* d_in, const int* in_sizes, int n_in,
                              void* d_out, int out_size, void* d_ws, size_t ws_size,
                              hipStream_t stream) {
    const float* x      = (const float*)d_in[0];
    const int*   ei     = (const int*)d_in[1];
    const float* noise  = (const float*)d_in[2];
    const float* W_proj = (const float*)d_in[3];
    const float* b_proj = (const float*)d_in[4];
    const float* W_gat  = (const float*)d_in[5];
    const float* a_src  = (const float*)d_in[6];
    const float* a_dst  = (const float*)d_in[7];
    const float* b_gat  = (const float*)d_in[8];
    const float* g1     = (const float*)d_in[9];
    const float* be1    = (const float*)d_in[10];
    const float* W_qkv  = (const float*)d_in[11];
    const float* b_qkv  = (const float*)d_in[12];
    const float* W_o    = (const float*)d_in[13];
    const float* b_o    = (const float*)d_in[14];
    const float* g2     = (const float*)d_in[15];
    const float* be2    = (const float*)d_in[16];
    const float* Wc1    = (const float*)d_in[17];
    const float* bc1    = (const float*)d_in[18];
    const float* gc     = (const float*)d_in[19];
    const float* bec    = (const float*)d_in[20];
    const float* Wc2    = (const float*)d_in[21];
    const float* bc2    = (const float*)d_in[22];
    float* out = (float*)d_out;

    float* xh    = (float*)d_ws;                 // 5,120,000
    float* gout  = xh + 5120000;                 // 5,120,000
    float* a_s   = gout + 5120000;               //   320,000
    float* a_d   = a_s + 320000;                 //   320,000
    int*   offs    = (int*)(a_d + 320000);       //    40,008
    int*   cursor  = offs + 40008;               //    40,000
    int*   csr_src = cursor + 40000;             // 1,320,000
    float* WTq   = (float*)(csr_src + 1320000);  //    49,152
    float* WoT   = WTq + 49152;                  //    16,384

    k_tr<<<(384 * 128 + 128 * 128 + 255) / 256, 256, 0, stream>>>(W_qkv, W_o, WTq, WoT);

    k_pg<<<T * N / MT, 256, 0, stream>>>(x, W_proj, b_proj, W_gat, a_src, a_dst,
                                         xh, a_s, a_d);

    hipMemsetAsync(cursor, 0, 40000 * sizeof(int), stream);
    k_hist<<<(T * EN + 255) / 256, 256, 0, stream>>>(ei, cursor);
    k_scan<<<T, 256, 0, stream>>>(cursor, offs);
    k_scatter<<<(T * EN + 255) / 256, 256, 0, stream>>>(ei, cursor, csr_src);

    k_aggc<<<T * N, 128, 0, stream>>>(offs, csr_src, a_s, a_d, xh, gout);

    k_node<<<N, 128, 0, stream>>>(gout, b_gat, g1, be1, WTq, b_qkv, WoT, b_o,
                                  g2, be2, noise, out);

    k_cls<<<(N + MT - 1) / MT, 256, 0, stream>>>(out, Wc1, bc1, gc, bec, Wc2, bc2, out);
}